// Round 5
// baseline (167.915 us; speedup 1.0000x reference)
//
#include <hip/hip_runtime.h>
#include <math.h>

// MutualInformationLoss: binary 256x256 occupancy map -> MI -> 1 - tanh(mi).
// R5: SINGLE-LAUNCH fusion. 512 blocks hist into private LDS bitmaps, publish
// 8KB slices with device-scope atomic stores (cross-XCD visible), set a magic
// done-flag (poison 0xAA != magic, so no pre-zeroing launch needed). Blocks
// 0..31 then OR-reduce all 512 slices (device-scope atomic loads bypass stale
// poison in L1/L2) and block 0 finalizes. Spinners are only 32 blocks ->
// non-spinners always drain -> deadlock-free at any occupancy >= 33 slots.
// Fixed harness overhead per timed iter: ~42us ws-poison fill + d_in restore.

#define NB 256
#define BM_WORDS 2048          // 65536 bins / 32
#define HGRID 512
#define HTHREADS 512
#define NRED 32                // reducer blocks (blocks 0..31)
#define CHUNK (BM_WORDS / NRED)  // 64 words per reducer
#define MAGIC 0x5151CAFEu

// ws layout (words): [0, SL) slices, [SL, SL+2048) final bitmap,
// [SL+2048, SL+2048+512) done flags, [SL+2560, SL+2592) done2 flags.
#define SL_WORDS (HGRID * BM_WORDS)

__device__ __forceinline__ void set_bin(unsigned int* bm, float a, float b) {
    // Exact replica of jnp: clip(x*255, 0, 255).astype(int32) (truncation).
    float va = fminf(fmaxf(a * 255.0f, 0.0f), 255.0f);
    float vb = fminf(fmaxf(b * 255.0f, 0.0f), 255.0f);
    int bin = ((int)va << 8) | (int)vb;
    atomicOr(&bm[bin >> 5], 1u << (bin & 31));
}

__device__ __forceinline__ void finalize_from_lds(unsigned int* w, float* rcs, float* red,
                                                  int t, float* out) {
    float partial = 0.0f;
    int r = 0, c = 0;
    if (t < NB) {
#pragma unroll
        for (int k = 0; k < 8; ++k) r += __popc(w[t * 8 + k]);
        rcs[t] = (float)r;
        const int wsel = t >> 5;
        const int bsel = t & 31;
        for (int i = 0; i < NB; ++i) c += (w[i * 8 + wsel] >> bsel) & 1;
    }
    __syncthreads();
    float S = 0.0f;
    if (t < NB) {
        for (int i = 0; i < NB; ++i) S += rcs[i];
        // mi = -log(S) - ( sum rc*log(rc/S) + sum cc*log(cc/S) ) / S
        // (eps=1e-10 in the reference denom perturbs mi by <1e-5; << 2e-2 tol)
        if (r > 0) partial += (float)r * logf((float)r / S);
        if (c > 0) partial += (float)c * logf((float)c / S);
        for (int off = 32; off > 0; off >>= 1) partial += __shfl_down(partial, off, 64);
        if ((t & 63) == 0) red[t >> 6] = partial;
    }
    __syncthreads();
    if (t == 0) {
        float B = red[0] + red[1] + red[2] + red[3];
        float mi = -logf(S) - B / S;
        out[0] = 1.0f - tanhf(mi);
    }
}

__device__ __forceinline__ void hist_body(const float* __restrict__ x,
                                          const float* __restrict__ y,
                                          unsigned int* bm, int n, int t) {
    const int n4 = n >> 2;
    const float4* __restrict__ x4 = (const float4*)x;
    const float4* __restrict__ y4 = (const float4*)y;
    const int nth = gridDim.x * blockDim.x;
    int i = blockIdx.x * blockDim.x + t;
    // Unroll-3: 6 independent float4 loads in flight (n=12.58M: exactly 4 iters).
    for (; i + 2 * nth < n4; i += 3 * nth) {
        float4 a0 = x4[i];           float4 b0 = y4[i];
        float4 a1 = x4[i + nth];     float4 b1 = y4[i + nth];
        float4 a2 = x4[i + 2 * nth]; float4 b2 = y4[i + 2 * nth];
        set_bin(bm, a0.x, b0.x); set_bin(bm, a0.y, b0.y);
        set_bin(bm, a0.z, b0.z); set_bin(bm, a0.w, b0.w);
        set_bin(bm, a1.x, b1.x); set_bin(bm, a1.y, b1.y);
        set_bin(bm, a1.z, b1.z); set_bin(bm, a1.w, b1.w);
        set_bin(bm, a2.x, b2.x); set_bin(bm, a2.y, b2.y);
        set_bin(bm, a2.z, b2.z); set_bin(bm, a2.w, b2.w);
    }
    for (; i < n4; i += nth) {
        float4 a = x4[i]; float4 b = y4[i];
        set_bin(bm, a.x, b.x); set_bin(bm, a.y, b.y);
        set_bin(bm, a.z, b.z); set_bin(bm, a.w, b.w);
    }
    for (int j = (n4 << 2) + blockIdx.x * blockDim.x + t; j < n; j += nth) {
        set_bin(bm, x[j], y[j]);
    }
}

// ---------------- single fused kernel ----------------

__global__ __launch_bounds__(HTHREADS, 2) void mi_fused(const float* __restrict__ x,
                                                        const float* __restrict__ y,
                                                        unsigned int* __restrict__ ws,
                                                        float* __restrict__ out,
                                                        int n) {
    __shared__ unsigned int bm[BM_WORDS];   // hist bitmap; reused as partials & final map
    __shared__ float rcs[NB];
    __shared__ float red[8];
    const int t = threadIdx.x;
    const int b = blockIdx.x;
    unsigned int* finalbm = ws + SL_WORDS;
    unsigned int* done    = ws + SL_WORDS + BM_WORDS;          // 512 flags
    unsigned int* done2   = ws + SL_WORDS + BM_WORDS + HGRID;  // 32 flags

    for (int k = t; k < BM_WORDS; k += HTHREADS) bm[k] = 0u;
    __syncthreads();

    hist_body(x, y, bm, n, t);
    __syncthreads();

    // Publish this block's slice with device-scope stores (cross-XCD visible),
    // then release the magic done flag.
    unsigned int* slice = ws + (size_t)b * BM_WORDS;
#pragma unroll
    for (int k = 0; k < BM_WORDS / HTHREADS; ++k) {
        int w = t + k * HTHREADS;
        __hip_atomic_store(&slice[w], bm[w], __ATOMIC_RELAXED, __HIP_MEMORY_SCOPE_AGENT);
    }
    __syncthreads();
    if (t == 0)
        __hip_atomic_store(&done[b], MAGIC, __ATOMIC_RELEASE, __HIP_MEMORY_SCOPE_AGENT);

    if (b >= NRED) return;  // 480 blocks exit; only 32 spin -> deadlock-free

    // ---- phase 2: wait for all 512 slices (per-thread spin on distinct flags) ----
    while (__hip_atomic_load(&done[t], __ATOMIC_ACQUIRE, __HIP_MEMORY_SCOPE_AGENT) != MAGIC)
        __builtin_amdgcn_s_sleep(8);
    __syncthreads();
    __threadfence();  // agent acquire: order subsequent reads
    __syncthreads();

    // OR-reduce words [b*CHUNK, (b+1)*CHUNK) across all 512 slices.
    // Thread map: 512 threads = 8 slice-groups x 64 words; 64 sweeps.
    {
        const int w = t & (CHUNK - 1);       // word within chunk (0..63)
        const int sg = t >> 6;               // slice group (0..7)
        unsigned int v = 0u;
        for (int s = sg; s < HGRID; s += 8) {
            v |= __hip_atomic_load(&ws[(size_t)s * BM_WORDS + b * CHUNK + w],
                                   __ATOMIC_RELAXED, __HIP_MEMORY_SCOPE_AGENT);
        }
        bm[t] = v;  // partials: 512 words (bm reused; prior use done)
        __syncthreads();
        if (t < CHUNK) {
            unsigned int r = bm[t];
#pragma unroll
            for (int g = 1; g < 8; ++g) r |= bm[g * CHUNK + t];
            __hip_atomic_store(&finalbm[b * CHUNK + t], r, __ATOMIC_RELAXED,
                               __HIP_MEMORY_SCOPE_AGENT);
        }
        __syncthreads();
        if (t == 0)
            __hip_atomic_store(&done2[b], MAGIC, __ATOMIC_RELEASE, __HIP_MEMORY_SCOPE_AGENT);
    }

    if (b != 0) return;

    // ---- phase 3: block 0 finalizes after all 32 chunk flags ----
    if (t < NRED) {
        while (__hip_atomic_load(&done2[t], __ATOMIC_ACQUIRE, __HIP_MEMORY_SCOPE_AGENT) != MAGIC)
            __builtin_amdgcn_s_sleep(8);
    }
    __syncthreads();
    __threadfence();
    __syncthreads();
    for (int k = t; k < BM_WORDS; k += HTHREADS)
        bm[k] = __hip_atomic_load(&finalbm[k], __ATOMIC_RELAXED, __HIP_MEMORY_SCOPE_AGENT);
    __syncthreads();
    finalize_from_lds(bm, rcs, red, t, out);
}

// ---------------- fallback path (small ws): atomic merge, 2 launches ----------------

__global__ void zero_kernel(unsigned int* __restrict__ bm) {
    int i = blockIdx.x * blockDim.x + threadIdx.x;
    if (i < BM_WORDS + 1) bm[i] = 0u;
}

__global__ __launch_bounds__(HTHREADS, 2) void hist_fused(const float* __restrict__ x,
                                                          const float* __restrict__ y,
                                                          unsigned int* __restrict__ gbm,
                                                          float* __restrict__ out,
                                                          int n) {
    __shared__ unsigned int bm[BM_WORDS];
    __shared__ float rcs[NB];
    __shared__ float red[8];
    __shared__ unsigned int ticket;
    const int t = threadIdx.x;

    for (int k = t; k < BM_WORDS; k += blockDim.x) bm[k] = 0u;
    __syncthreads();
    hist_body(x, y, bm, n, t);
    __syncthreads();
    for (int k = t; k < BM_WORDS; k += blockDim.x) {
        unsigned int v = bm[k];
        if (v) {
            unsigned int g = gbm[k];
            if (v & ~g) atomicOr(&gbm[k], v);
        }
    }
    __syncthreads();
    if (t == 0) {
        __threadfence();
        ticket = __hip_atomic_fetch_add(&gbm[BM_WORDS], 1u, __ATOMIC_ACQ_REL,
                                        __HIP_MEMORY_SCOPE_AGENT);
    }
    __syncthreads();
    if (ticket != gridDim.x - 1) return;
    __threadfence();
    for (int k = t; k < BM_WORDS; k += blockDim.x)
        bm[k] = __hip_atomic_load(&gbm[k], __ATOMIC_RELAXED, __HIP_MEMORY_SCOPE_AGENT);
    __syncthreads();
    finalize_from_lds(bm, rcs, red, t, out);
}

extern "C" void kernel_launch(void* const* d_in, const int* in_sizes, int n_in,
                              void* d_out, int out_size, void* d_ws, size_t ws_size,
                              hipStream_t stream) {
    const float* x = (const float*)d_in[0];  // I_complementary -> row bins
    const float* y = (const float*)d_in[1];  // I_target        -> col bins
    float* out = (float*)d_out;
    unsigned int* ws = (unsigned int*)d_ws;
    const int n = in_sizes[0];

    const size_t need = (size_t)(SL_WORDS + BM_WORDS + HGRID + NRED) * sizeof(unsigned int);
    if (ws_size >= need) {
        mi_fused<<<HGRID, HTHREADS, 0, stream>>>(x, y, ws, out, n);
    } else {
        zero_kernel<<<(BM_WORDS + 256) / 256, 256, 0, stream>>>(ws);
        hist_fused<<<HGRID, HTHREADS, 0, stream>>>(x, y, ws, out, n);
    }
}

// Round 6
// 123.069 us; speedup vs baseline: 1.3644x; 1.3644x over previous
//
#include <hip/hip_runtime.h>
#include <math.h>

// MutualInformationLoss: binary 256x256 occupancy map -> MI -> 1 - tanh(mi).
// R6: R3's two-kernel structure (in-kernel cross-XCD sync proved 40us slower
// than a kernel boundary in R5) + software-pipelined hist: depth-2 register
// double-buffer keeps global loads in flight during the LDS-atomic scatter
// (R3's body had zero loads outstanding during processing -> MLP-starved).
// Kernel boundary provides the cross-XCD release/acquire for slice reads.
// Fixed harness overhead per iter: ~42us ws poison fill + ~32us d_in restore.

#define NB 256
#define BM_WORDS 2048          // 65536 bins / 32
#define HGRID 512
#define HTHREADS 512
#define RGRID 64
#define RTHREADS 256

// ws layout (words): [0, SL_WORDS) slices, [SL, SL+BM_WORDS) final bitmap,
// [SL+BM_WORDS] arrival counter.
#define SL_WORDS (HGRID * BM_WORDS)

__device__ __forceinline__ void set_bin(unsigned int* bm, float a, float b) {
    // Exact replica of jnp: clip(x*255, 0, 255).astype(int32) (truncation).
    float va = fminf(fmaxf(a * 255.0f, 0.0f), 255.0f);
    float vb = fminf(fmaxf(b * 255.0f, 0.0f), 255.0f);
    int bin = ((int)va << 8) | (int)vb;
    atomicOr(&bm[bin >> 5], 1u << (bin & 31));
}

__device__ __forceinline__ void set_bin4(unsigned int* bm, float4 a, float4 b) {
    set_bin(bm, a.x, b.x); set_bin(bm, a.y, b.y);
    set_bin(bm, a.z, b.z); set_bin(bm, a.w, b.w);
}

__device__ __forceinline__ void finalize_from_lds(unsigned int* w, float* rcs, float* red,
                                                  int t, float* out) {
    float partial = 0.0f;
    int r = 0, c = 0;
    if (t < NB) {
        // Row count for row t: words [t*8, t*8+8)
#pragma unroll
        for (int k = 0; k < 8; ++k) r += __popc(w[t * 8 + k]);
        rcs[t] = (float)r;
        // Column count for column t: bit (t&31) of word i*8 + (t>>5), rows i
        const int wsel = t >> 5;
        const int bsel = t & 31;
        for (int i = 0; i < NB; ++i) c += (w[i * 8 + wsel] >> bsel) & 1;
    }
    __syncthreads();
    float S = 0.0f;
    if (t < NB) {
        for (int i = 0; i < NB; ++i) S += rcs[i];
        // mi = -log(S) - ( sum rc*log(rc/S) + sum cc*log(cc/S) ) / S
        // (eps=1e-10 in the reference denom perturbs mi by <1e-5; << 2e-2 tol)
        if (r > 0) partial += (float)r * logf((float)r / S);
        if (c > 0) partial += (float)c * logf((float)c / S);
        for (int off = 32; off > 0; off >>= 1) partial += __shfl_down(partial, off, 64);
        if ((t & 63) == 0) red[t >> 6] = partial;
    }
    __syncthreads();
    if (t == 0) {
        float B = red[0] + red[1] + red[2] + red[3];
        float mi = -logf(S) - B / S;
        out[0] = 1.0f - tanhf(mi);
    }
}

__device__ __forceinline__ void hist_body(const float* __restrict__ x,
                                          const float* __restrict__ y,
                                          unsigned int* bm, int n, int t) {
    const int n4 = n >> 2;
    const float4* __restrict__ x4 = (const float4*)x;
    const float4* __restrict__ y4 = (const float4*)y;
    const int nth = gridDim.x * blockDim.x;
    int i = blockIdx.x * blockDim.x + t;

    // Depth-2 software pipeline: next pair's loads issue BEFORE current pair's
    // LDS-atomic scatter, so VMEM stays busy through processing.
    // (n=12.58M, nth=262144: n4/nth = 12 exact iterations, no tail.)
    if (i < n4) {
        float4 a0 = x4[i];
        float4 b0 = y4[i];
        int inext = i + nth;
        while (inext < n4) {
            float4 a1 = x4[inext];
            float4 b1 = y4[inext];
            inext += nth;
            set_bin4(bm, a0, b0);
            a0 = a1; b0 = b1;
        }
        set_bin4(bm, a0, b0);
    }
    // scalar tail (n % 4)
    for (int j = (n4 << 2) + blockIdx.x * blockDim.x + t; j < n; j += nth) {
        set_bin(bm, x[j], y[j]);
    }
}

// ---------------- main path ----------------

__global__ __launch_bounds__(HTHREADS, 2) void hist_slices(const float* __restrict__ x,
                                                           const float* __restrict__ y,
                                                           unsigned int* __restrict__ ws,
                                                           int n) {
    __shared__ unsigned int bm[BM_WORDS];
    const int t = threadIdx.x;
    if (blockIdx.x == 0 && t == 0) ws[SL_WORDS + BM_WORDS] = 0u;  // arrival counter
    for (int k = t; k < BM_WORDS; k += HTHREADS) bm[k] = 0u;
    __syncthreads();

    hist_body(x, y, bm, n, t);
    __syncthreads();

    // Publish private bitmap to this block's slice: plain coalesced uint4 stores.
    // Cross-XCD visibility comes from the kernel boundary before reduce_finalize.
    uint4 v;
    v.x = bm[4 * t];     v.y = bm[4 * t + 1];
    v.z = bm[4 * t + 2]; v.w = bm[4 * t + 3];
    ((uint4*)(ws + (size_t)blockIdx.x * BM_WORDS))[t] = v;
}

__global__ __launch_bounds__(RTHREADS) void reduce_finalize(unsigned int* __restrict__ ws,
                                                            float* __restrict__ out) {
    __shared__ uint4 p4[RTHREADS];
    __shared__ unsigned int w[BM_WORDS];
    __shared__ float rcs[NB];
    __shared__ float red[8];
    __shared__ unsigned int ticket;
    const int t = threadIdx.x;
    const int b = blockIdx.x;
    unsigned int* finalbm = ws + SL_WORDS;
    unsigned int* counter = ws + SL_WORDS + BM_WORDS;

    // Block b OR-reduces uint4 indices [b*8, b*8+8) across all HGRID slices.
    const uint4* s4 = (const uint4*)ws;          // slice s: s4[s*512 + q]
    const int q = b * 8 + (t & 7);
    uint4 v = make_uint4(0u, 0u, 0u, 0u);
#pragma unroll 4
    for (int k = 0; k < HGRID / 32; ++k) {       // 32 slices per sweep
        int s = (t >> 3) + 32 * k;
        uint4 g = s4[(size_t)s * (BM_WORDS / 4) + q];
        v.x |= g.x; v.y |= g.y; v.z |= g.z; v.w |= g.w;
    }
    p4[t] = v;
    __syncthreads();
    if (t < 8) {
        uint4 r = p4[t];
        for (int k = 1; k < 32; ++k) {
            uint4 g = p4[t + 8 * k];
            r.x |= g.x; r.y |= g.y; r.z |= g.z; r.w |= g.w;
        }
        ((uint4*)finalbm)[b * 8 + t] = r;
    }
    __syncthreads();

    // Last-block-done among RGRID blocks (counter zeroed by hist_slices).
    if (t == 0) {
        __threadfence();
        ticket = atomicAdd(counter, 1u);
    }
    __syncthreads();
    if (ticket != gridDim.x - 1) return;

    __threadfence();
    for (int k = t; k < BM_WORDS; k += RTHREADS)
        w[k] = __hip_atomic_load(&finalbm[k], __ATOMIC_RELAXED, __HIP_MEMORY_SCOPE_AGENT);
    __syncthreads();
    finalize_from_lds(w, rcs, red, t, out);
}

// ---------------- fallback path (small ws): atomic merge, 2 launches ----------------

__global__ void zero_kernel(unsigned int* __restrict__ bm) {
    int i = blockIdx.x * blockDim.x + threadIdx.x;
    if (i < BM_WORDS + 1) bm[i] = 0u;
}

__global__ __launch_bounds__(HTHREADS, 2) void hist_fused(const float* __restrict__ x,
                                                          const float* __restrict__ y,
                                                          unsigned int* __restrict__ gbm,
                                                          float* __restrict__ out,
                                                          int n) {
    __shared__ unsigned int bm[BM_WORDS];
    __shared__ float rcs[NB];
    __shared__ float red[8];
    __shared__ unsigned int ticket;
    const int t = threadIdx.x;

    for (int k = t; k < BM_WORDS; k += blockDim.x) bm[k] = 0u;
    __syncthreads();
    hist_body(x, y, bm, n, t);
    __syncthreads();
    for (int k = t; k < BM_WORDS; k += blockDim.x) {
        unsigned int v = bm[k];
        if (v) {
            unsigned int g = gbm[k];
            if (v & ~g) atomicOr(&gbm[k], v);
        }
    }
    __syncthreads();
    if (t == 0) {
        __threadfence();
        ticket = __hip_atomic_fetch_add(&gbm[BM_WORDS], 1u, __ATOMIC_ACQ_REL,
                                        __HIP_MEMORY_SCOPE_AGENT);
    }
    __syncthreads();
    if (ticket != gridDim.x - 1) return;
    __threadfence();
    for (int k = t; k < BM_WORDS; k += blockDim.x)
        bm[k] = __hip_atomic_load(&gbm[k], __ATOMIC_RELAXED, __HIP_MEMORY_SCOPE_AGENT);
    __syncthreads();
    finalize_from_lds(bm, rcs, red, t, out);
}

extern "C" void kernel_launch(void* const* d_in, const int* in_sizes, int n_in,
                              void* d_out, int out_size, void* d_ws, size_t ws_size,
                              hipStream_t stream) {
    const float* x = (const float*)d_in[0];  // I_complementary -> row bins
    const float* y = (const float*)d_in[1];  // I_target        -> col bins
    float* out = (float*)d_out;
    unsigned int* ws = (unsigned int*)d_ws;
    const int n = in_sizes[0];

    const size_t need = (size_t)(SL_WORDS + BM_WORDS + 1) * sizeof(unsigned int);
    if (ws_size >= need) {
        hist_slices<<<HGRID, HTHREADS, 0, stream>>>(x, y, ws, n);
        reduce_finalize<<<RGRID, RTHREADS, 0, stream>>>(ws, out);
    } else {
        zero_kernel<<<(BM_WORDS + 256) / 256, 256, 0, stream>>>(ws);
        hist_fused<<<HGRID, HTHREADS, 0, stream>>>(x, y, ws, out, n);
    }
}